// Round 3
// baseline (109.180 us; speedup 1.0000x reference)
//
#include <hip/hip_runtime.h>

#define T_TOTAL 4194304
#define S 16                        // timesteps per thread (one segment)
#define NTHREADS 256
#define BLOCK_T (NTHREADS * S)      // 4096 timesteps per window
#define NWIN 4                      // sequential windows per block (pipeline depth 2)
#define NBLOCKS (T_TOTAL / (BLOCK_T * NWIN))   // 256 blocks = 1 per CU
#define HALO_SEG 4                  // 64 warmup steps; ||A^64|| ~ 1e-8
#define NSEG (NTHREADS + HALO_SEG)  // 260

struct M22 { float m00, m01, m10, m11; };
__device__ __forceinline__ M22 mmul(const M22& X, const M22& Y) {
    M22 r;
    r.m00 = fmaf(X.m00, Y.m00, X.m01 * Y.m10);
    r.m01 = fmaf(X.m00, Y.m01, X.m01 * Y.m11);
    r.m10 = fmaf(X.m10, Y.m00, X.m11 * Y.m10);
    r.m11 = fmaf(X.m10, Y.m01, X.m11 * Y.m11);
    return r;
}

struct alignas(16) F16 { float f[16]; };
__device__ __forceinline__ void load16(F16& d, const float* __restrict__ p) {
    const float4* q = (const float4*)p;     // bases 64B-aligned (t % 16 == 0)
    float4 a0 = q[0], a1 = q[1], a2 = q[2], a3 = q[3];
    *(float4*)&d.f[0]  = a0;
    *(float4*)&d.f[4]  = a1;
    *(float4*)&d.f[8]  = a2;
    *(float4*)&d.f[12] = a3;
}

// 256 blocks, 1/CU, each walks 4 consecutive windows with register prefetch of
// the NEXT window overlapping compute+store of the CURRENT one. This replaces
// the chip-wide [read burst][compute][write burst] pattern (all grid-resident
// variants so far) with continuous mixed read+write traffic. Windows 1..3 get
// their halo c's carried from the previous window's lc tail (exact same
// truncation as the load-based halo; no extra loads, no halo recompute).
__global__ __launch_bounds__(NTHREADS, 1)
void pinn_rnn_kernel(const float* __restrict__ x0p,
                     const float* __restrict__ u,
                     const float* __restrict__ td,
                     const float* __restrict__ WA,
                     const float* __restrict__ bA,
                     const float* __restrict__ WB,
                     const float* __restrict__ bB,
                     float* __restrict__ out)
{
    __shared__ float2 lc[NSEG];        // segment zero-state responses (~2 KB)
    __shared__ float2 lout[BLOCK_T];   // output transpose staging (32 KB)

    const int tid  = threadIdx.x;
    const int base = blockIdx.x * (BLOCK_T * NWIN);

    const float a00 = WA[0], a01 = WA[1], a10 = WA[2], a11 = WA[3];
    const float w00 = WB[0], w01 = WB[1], w10 = WB[2], w11 = WB[3];
    const float bc0 = bA[0] + bB[0];
    const float bc1 = bA[1] + bB[1];

    const float* u0 = u;
    const float* u1 = u + T_TOTAL;

    // ---- window 0 loads (own chunk + halo) ----
    F16 U0c, U1c, DTc;
    {
        const int t0 = base + tid * S;
        load16(U0c, u0 + t0);
        load16(U1c, u1 + t0);
        load16(DTc, td + t0);
    }

    F16 H0, H1;
    float X0 = 0.f, X1 = 0.f;
    const bool halo_owner = (tid < HALO_SEG);
    if (halo_owner) {
        if (blockIdx.x != 0) {
            const int th = base - HALO_SEG * S + tid * S;
            load16(H0, u0 + th);
            load16(H1, u1 + th);
        } else {
            X0 = x0p[0]; X1 = x0p[1];
        }
    }

    // ---- powers of A (uniform) ----
    M22 A   = { a00, a01, a10, a11 };
    M22 A2  = mmul(A,  A );
    M22 A4  = mmul(A2, A2);
    M22 A8  = mmul(A4, A4);
    M22 M   = mmul(A8, A8);   // A^16
    M22 Mp2 = mmul(M,  M );   // A^32
    M22 Mp3 = mmul(Mp2, M);   // A^48

    // ---- phase 1 (window 0): zero-state responses ----
    {
        float x0v = 0.f, x1v = 0.f;
        #pragma unroll
        for (int j = 0; j < S; ++j) {
            float v0 = fmaf(w00, U0c.f[j], fmaf(w01, U1c.f[j], bc0));
            float v1 = fmaf(w10, U0c.f[j], fmaf(w11, U1c.f[j], bc1));
            float n0 = fmaf(a00, x0v, fmaf(a01, x1v, v0));
            float n1 = fmaf(a10, x0v, fmaf(a11, x1v, v1));
            x0v = n0; x1v = n1;
        }
        lc[tid + HALO_SEG] = make_float2(x0v, x1v);
    }
    if (halo_owner) {
        if (blockIdx.x != 0) {
            float x0v = 0.f, x1v = 0.f;
            #pragma unroll
            for (int j = 0; j < S; ++j) {
                float v0 = fmaf(w00, H0.f[j], fmaf(w01, H1.f[j], bc0));
                float v1 = fmaf(w10, H0.f[j], fmaf(w11, H1.f[j], bc1));
                float n0 = fmaf(a00, x0v, fmaf(a01, x1v, v0));
                float n1 = fmaf(a10, x0v, fmaf(a11, x1v, v1));
                x0v = n0; x1v = n1;
            }
            lc[tid] = make_float2(x0v, x1v);
        } else {
            lc[tid] = make_float2(0.f, 0.f);   // virtual history = 0; x0 via P below
        }
    }

    __syncthreads();   // lc ready for window 0

    F16 U0n, U1n, DTn;   // prefetch buffers

    for (int w = 0; w < NWIN; ++w) {
        // ---- issue NEXT window's loads first: they drain under this
        //      window's compute + store (the pipeline) ----
        if (w + 1 < NWIN) {
            const int tn = base + (w + 1) * BLOCK_T + tid * S;
            load16(U0n, u0 + tn);
            load16(U1n, u1 + tn);
            load16(DTn, td + tn);
        }

        // ---- x_in + phase 2 into swizzled lout ----
        float2 hc;   // halo carry for next window (this window's lc tail)
        {
            float2 c1 = lc[tid + 3], c2 = lc[tid + 2], c3 = lc[tid + 1], c4 = lc[tid];
            if (halo_owner) hc = lc[NTHREADS + tid];
            float xi0 = c1.x
                      + fmaf(M.m00,   c2.x, M.m01   * c2.y)
                      + fmaf(Mp2.m00, c3.x, Mp2.m01 * c3.y)
                      + fmaf(Mp3.m00, c4.x, Mp3.m01 * c4.y);
            float xi1 = c1.y
                      + fmaf(M.m10,   c2.x, M.m11   * c2.y)
                      + fmaf(Mp2.m10, c3.x, Mp2.m11 * c3.y)
                      + fmaf(Mp3.m10, c4.x, Mp3.m11 * c4.y);
            if (w == 0 && blockIdx.x == 0 && halo_owner) {   // exact A^(16*tid) * x_0
                M22 P;
                if      (tid == 0) P = { 1.f, 0.f, 0.f, 1.f };
                else if (tid == 1) P = M;
                else if (tid == 2) P = Mp2;
                else               P = Mp3;
                xi0 += fmaf(P.m00, X0, P.m01 * X1);
                xi1 += fmaf(P.m10, X0, P.m11 * X1);
            }
            const int xm = tid & 14;
            float2* lrow = lout + tid * S;
            float x0v = xi0, x1v = xi1;
            #pragma unroll
            for (int j = 0; j < S; ++j) {
                float v0 = fmaf(w00, U0c.f[j], fmaf(w01, U1c.f[j], bc0));
                float v1 = fmaf(w10, U0c.f[j], fmaf(w11, U1c.f[j], bc1));
                float n0 = fmaf(a00, x0v, fmaf(a01, x1v, v0));
                float n1 = fmaf(a10, x0v, fmaf(a11, x1v, v1));
                float cc = U0c.f[j] * DTc.f[j];
                float sn, cs;
                __sincosf(U1c.f[j], &sn, &cs);
                lrow[j ^ xm] = make_float2(fmaf(cc, cs, x0v) - n0,
                                           fmaf(cc, sn, x1v) - n1);
                x0v = n0; x1v = n1;
            }
        }
        __syncthreads();   // lout ready; lc reads of this window done

        // ---- copy-out this window (coalesced float4) ----
        {
            const float4* lo4 = (const float4*)lout;
            float4* og = (float4*)out + ((base + w * BLOCK_T) >> 1);
            #pragma unroll
            for (int m = 0; m < 8; ++m) {
                int f    = m * NTHREADS + tid;
                int i0   = f << 1;
                int slot = i0 ^ ((i0 >> 4) & 14);
                og[f] = lo4[slot >> 1];
            }
        }

        // ---- phase 1 for next window (consumes the prefetch) ----
        if (w + 1 < NWIN) {
            float x0v = 0.f, x1v = 0.f;
            #pragma unroll
            for (int j = 0; j < S; ++j) {
                float v0 = fmaf(w00, U0n.f[j], fmaf(w01, U1n.f[j], bc0));
                float v1 = fmaf(w10, U0n.f[j], fmaf(w11, U1n.f[j], bc1));
                float n0 = fmaf(a00, x0v, fmaf(a01, x1v, v0));
                float n1 = fmaf(a10, x0v, fmaf(a11, x1v, v1));
                x0v = n0; x1v = n1;
            }
            lc[tid + HALO_SEG] = make_float2(x0v, x1v);
            if (halo_owner) lc[tid] = hc;   // carried halo: prev window's tail c's

            // rotate prefetch -> current (register moves; loop body stays rolled)
            U0c = U0n; U1c = U1n; DTc = DTn;
            __syncthreads();   // lc ready for next window; lout free to overwrite
        }
    }
}

extern "C" void kernel_launch(void* const* d_in, const int* in_sizes, int n_in,
                              void* d_out, int out_size, void* d_ws, size_t ws_size,
                              hipStream_t stream) {
    const float* x0p = (const float*)d_in[0];
    const float* u   = (const float*)d_in[1];
    const float* td  = (const float*)d_in[2];
    const float* WA  = (const float*)d_in[3];
    const float* bA  = (const float*)d_in[4];
    const float* WB  = (const float*)d_in[5];
    const float* bB  = (const float*)d_in[6];
    float* outp = (float*)d_out;

    dim3 grid(NBLOCKS);      // 256 blocks, 1 per CU, 4 sequential windows each
    dim3 block(NTHREADS);
    pinn_rnn_kernel<<<grid, block, 0, stream>>>(x0p, u, td, WA, bA, WB, bB, outp);
}

// Round 4
// 105.356 us; speedup vs baseline: 1.0363x; 1.0363x over previous
//
#include <hip/hip_runtime.h>

#define T_TOTAL 4194304
#define S 16                       // timesteps per thread (one segment)
#define NTHREADS 256
#define BLOCK_T (NTHREADS * S)     // 4096 timesteps per window
#define WPB 2                      // windows per block (software pipeline)
#define HALO_SEG 4                 // 64 warmup steps; ||A^64|| ~ 1e-8
#define NSEG (NTHREADS + HALO_SEG) // 260

struct M22 { float m00, m01, m10, m11; };
__device__ __forceinline__ M22 mmul(const M22& X, const M22& Y) {
    M22 r;
    r.m00 = fmaf(X.m00, Y.m00, X.m01 * Y.m10);
    r.m01 = fmaf(X.m00, Y.m01, X.m01 * Y.m11);
    r.m10 = fmaf(X.m10, Y.m00, X.m11 * Y.m10);
    r.m11 = fmaf(X.m10, Y.m01, X.m11 * Y.m11);
    return r;
}

struct alignas(16) F16 { float f[16]; };
__device__ __forceinline__ void load16(F16& d, const float* __restrict__ p) {
    const float4* q = (const float4*)p;     // bases 64B-aligned (t % 16 == 0)
    float4 a0 = q[0], a1 = q[1], a2 = q[2], a3 = q[3];
    *(float4*)&d.f[0]  = a0;
    *(float4*)&d.f[4]  = a1;
    *(float4*)&d.f[8]  = a2;
    *(float4*)&d.f[12] = a3;
}

__global__ __launch_bounds__(NTHREADS, 2)   // 2 blocks/CU (LDS 70KB), VGPR<=256
void pinn_rnn_kernel(const float* __restrict__ x0p,
                     const float* __restrict__ u,
                     const float* __restrict__ td,
                     const float* __restrict__ WA,
                     const float* __restrict__ bA,
                     const float* __restrict__ WB,
                     const float* __restrict__ bB,
                     float* __restrict__ out)
{
    __shared__ float2 lc0[NSEG], lc1[NSEG];        // zero-state responses (2x2KB)
    __shared__ float2 lout0[BLOCK_T], lout1[BLOCK_T]; // output transposes (2x32KB)

    const int tid = threadIdx.x;
    const int B0  = blockIdx.x * (WPB * BLOCK_T);  // window 0 start
    const int B1  = B0 + BLOCK_T;                  // window 1 start

    const float a00 = WA[0], a01 = WA[1], a10 = WA[2], a11 = WA[3];
    const float w00 = WB[0], w01 = WB[1], w10 = WB[2], w11 = WB[3];
    const float bc0 = bA[0] + bB[0];
    const float bc1 = bA[1] + bB[1];

    const float* u0 = u;
    const float* u1 = u + T_TOTAL;

    // ---- W0 loads (own chunk + halo) ----
    const int t0 = B0 + tid * S;
    F16 U0a, U1a, DTa;
    load16(U0a, u0 + t0);
    load16(U1a, u1 + t0);
    load16(DTa, td + t0);

    F16 H0, H1;
    float X0 = 0.f, X1 = 0.f;
    const bool halo_owner = (tid < HALO_SEG);
    if (halo_owner) {
        if (blockIdx.x != 0) {
            const int th = B0 - HALO_SEG * S + tid * S;
            load16(H0, u0 + th);
            load16(H1, u1 + th);
        } else {
            X0 = x0p[0]; X1 = x0p[1];
            #pragma unroll
            for (int o = 0; o < 4; ++o) { *(float4*)&H0.f[o*4] = make_float4(0,0,0,0);
                                          *(float4*)&H1.f[o*4] = make_float4(0,0,0,0); }
        }
    }

    // ---- powers of A (uniform) ----
    M22 A   = { a00, a01, a10, a11 };
    M22 A2  = mmul(A,  A );
    M22 A4  = mmul(A2, A2);
    M22 A8  = mmul(A4, A4);
    M22 M   = mmul(A8, A8);   // A^16
    M22 Mp2 = mmul(M,  M );   // A^32
    M22 Mp3 = mmul(Mp2, M);   // A^48

    // ---- phase 1 (W0): zero-state responses ----
    {
        float x0v = 0.f, x1v = 0.f;
        #pragma unroll
        for (int j = 0; j < S; ++j) {
            float v0 = fmaf(w00, U0a.f[j], fmaf(w01, U1a.f[j], bc0));
            float v1 = fmaf(w10, U0a.f[j], fmaf(w11, U1a.f[j], bc1));
            float n0 = fmaf(a00, x0v, fmaf(a01, x1v, v0));
            float n1 = fmaf(a10, x0v, fmaf(a11, x1v, v1));
            x0v = n0; x1v = n1;
        }
        lc0[tid + HALO_SEG] = make_float2(x0v, x1v);
    }
    if (halo_owner) {
        float x0v = 0.f, x1v = 0.f;
        #pragma unroll
        for (int j = 0; j < S; ++j) {
            float v0 = fmaf(w00, H0.f[j], fmaf(w01, H1.f[j], bc0));
            float v1 = fmaf(w10, H0.f[j], fmaf(w11, H1.f[j], bc1));
            float n0 = fmaf(a00, x0v, fmaf(a01, x1v, v0));
            float n1 = fmaf(a10, x0v, fmaf(a11, x1v, v1));
            x0v = n0; x1v = n1;
        }
        lc0[tid] = make_float2(x0v, x1v);
        if (blockIdx.x == 0) lc0[tid] = make_float2(0.f, 0.f);
    }

    // ---- issue W1 loads NOW: they drain while W0 phase-2/stores run ----
    const int t1 = B1 + tid * S;
    F16 U0b, U1b, DTb;
    load16(U0b, u0 + t1);
    load16(U1b, u1 + t1);
    load16(DTb, td + t1);

    __syncthreads();   // A: lc0 ready

    // W1's halo c's are W0's last 4 segment c's — no loads, no compute
    if (halo_owner) lc1[tid] = lc0[NTHREADS + tid];

    // ---- x_in(W0) + phase 2 (W0) into swizzled lout0 ----
    {
        float2 c1 = lc0[tid + 3], c2 = lc0[tid + 2], c3 = lc0[tid + 1], c4 = lc0[tid];
        float xi0 = c1.x
                  + fmaf(M.m00,   c2.x, M.m01   * c2.y)
                  + fmaf(Mp2.m00, c3.x, Mp2.m01 * c3.y)
                  + fmaf(Mp3.m00, c4.x, Mp3.m01 * c4.y);
        float xi1 = c1.y
                  + fmaf(M.m10,   c2.x, M.m11   * c2.y)
                  + fmaf(Mp2.m10, c3.x, Mp2.m11 * c3.y)
                  + fmaf(Mp3.m10, c4.x, Mp3.m11 * c4.y);
        if (blockIdx.x == 0 && halo_owner) {   // exact A^(16*tid) * x_0
            M22 P;
            if      (tid == 0) P = { 1.f, 0.f, 0.f, 1.f };
            else if (tid == 1) P = M;
            else if (tid == 2) P = Mp2;
            else               P = Mp3;
            xi0 += fmaf(P.m00, X0, P.m01 * X1);
            xi1 += fmaf(P.m10, X0, P.m11 * X1);
        }
        const int xm = tid & 14;
        float2* lrow = lout0 + tid * S;
        float x0v = xi0, x1v = xi1;
        #pragma unroll
        for (int j = 0; j < S; ++j) {
            float v0 = fmaf(w00, U0a.f[j], fmaf(w01, U1a.f[j], bc0));
            float v1 = fmaf(w10, U0a.f[j], fmaf(w11, U1a.f[j], bc1));
            float n0 = fmaf(a00, x0v, fmaf(a01, x1v, v0));
            float n1 = fmaf(a10, x0v, fmaf(a11, x1v, v1));
            float cc = U0a.f[j] * DTa.f[j];
            float sn, cs;
            __sincosf(U1a.f[j], &sn, &cs);
            lrow[j ^ xm] = make_float2(fmaf(cc, cs, x0v) - n0,
                                       fmaf(cc, sn, x1v) - n1);
            x0v = n0; x1v = n1;
        }
    }
    __syncthreads();   // B: lout0 + lc1[0..3] ready

    // ---- copy-out W0 (coalesced), then phase 1 (W1) ----
    {
        const float4* lo4 = (const float4*)lout0;
        float4* og = (float4*)out + (B0 >> 1);
        #pragma unroll
        for (int m = 0; m < 8; ++m) {
            int f    = m * NTHREADS + tid;
            int i0   = f << 1;
            int slot = i0 ^ ((i0 >> 4) & 14);
            og[f] = lo4[slot >> 1];
        }
    }
    {
        float x0v = 0.f, x1v = 0.f;
        #pragma unroll
        for (int j = 0; j < S; ++j) {
            float v0 = fmaf(w00, U0b.f[j], fmaf(w01, U1b.f[j], bc0));
            float v1 = fmaf(w10, U0b.f[j], fmaf(w11, U1b.f[j], bc1));
            float n0 = fmaf(a00, x0v, fmaf(a01, x1v, v0));
            float n1 = fmaf(a10, x0v, fmaf(a11, x1v, v1));
            x0v = n0; x1v = n1;
        }
        lc1[tid + HALO_SEG] = make_float2(x0v, x1v);
    }
    __syncthreads();   // C: lc1 ready

    // ---- x_in(W1) + phase 2 (W1) into swizzled lout1 ----
    {
        float2 c1 = lc1[tid + 3], c2 = lc1[tid + 2], c3 = lc1[tid + 1], c4 = lc1[tid];
        float xi0 = c1.x
                  + fmaf(M.m00,   c2.x, M.m01   * c2.y)
                  + fmaf(Mp2.m00, c3.x, Mp2.m01 * c3.y)
                  + fmaf(Mp3.m00, c4.x, Mp3.m01 * c4.y);
        float xi1 = c1.y
                  + fmaf(M.m10,   c2.x, M.m11   * c2.y)
                  + fmaf(Mp2.m10, c3.x, Mp2.m11 * c3.y)
                  + fmaf(Mp3.m10, c4.x, Mp3.m11 * c4.y);
        const int xm = tid & 14;
        float2* lrow = lout1 + tid * S;
        float x0v = xi0, x1v = xi1;
        #pragma unroll
        for (int j = 0; j < S; ++j) {
            float v0 = fmaf(w00, U0b.f[j], fmaf(w01, U1b.f[j], bc0));
            float v1 = fmaf(w10, U0b.f[j], fmaf(w11, U1b.f[j], bc1));
            float n0 = fmaf(a00, x0v, fmaf(a01, x1v, v0));
            float n1 = fmaf(a10, x0v, fmaf(a11, x1v, v1));
            float cc = U0b.f[j] * DTb.f[j];
            float sn, cs;
            __sincosf(U1b.f[j], &sn, &cs);
            lrow[j ^ xm] = make_float2(fmaf(cc, cs, x0v) - n0,
                                       fmaf(cc, sn, x1v) - n1);
            x0v = n0; x1v = n1;
        }
    }
    __syncthreads();   // D: lout1 ready

    // ---- copy-out W1 (coalesced) ----
    {
        const float4* lo4 = (const float4*)lout1;
        float4* og = (float4*)out + (B1 >> 1);
        #pragma unroll
        for (int m = 0; m < 8; ++m) {
            int f    = m * NTHREADS + tid;
            int i0   = f << 1;
            int slot = i0 ^ ((i0 >> 4) & 14);
            og[f] = lo4[slot >> 1];
        }
    }
}

extern "C" void kernel_launch(void* const* d_in, const int* in_sizes, int n_in,
                              void* d_out, int out_size, void* d_ws, size_t ws_size,
                              hipStream_t stream) {
    const float* x0p = (const float*)d_in[0];
    const float* u   = (const float*)d_in[1];
    const float* td  = (const float*)d_in[2];
    const float* WA  = (const float*)d_in[3];
    const float* bA  = (const float*)d_in[4];
    const float* WB  = (const float*)d_in[5];
    const float* bB  = (const float*)d_in[6];
    float* outp = (float*)d_out;

    dim3 grid(T_TOTAL / (WPB * BLOCK_T));   // 512 blocks, 2 pipelined windows each
    dim3 block(NTHREADS);
    pinn_rnn_kernel<<<grid, block, 0, stream>>>(x0p, u, td, WA, bA, WB, bB, outp);
}